// Round 2
// baseline (6286.594 us; speedup 1.0000x reference)
//
#include <hip/hip_runtime.h>
#include <stdint.h>

// ---------------------------------------------------------------------------
// EditorActorCritic: embed GEMM -> input-proj GEMM -> clustered LSTM scan ->
// actor/critic head GEMMs.  fp32/bf16 input dtype detected at runtime;
// compute is bf16 MFMA, fp32 accumulate.
// Round-8 change: EXCHANGE-FREE LSTM.  One 1024-thread WG (16 waves) per
// 16-row batch cluster covers the FULL hid dim: wave w owns hid slice
// [w*16, w*16+16) for all 4 gates, so every cell's 4 gate values land in the
// owning lane's accumulators -> no z-exchange, no h-exchange, no atomics.
// Wh (constant, 512KB, L2-resident) is STREAMED as B-fragments each step
// (4 x b128 per ks, 2-deep reg dbuf) instead of register-pinned; h tile is a
// double-buffered XOR-swizzled LDS tile -> ONE barrier per step, waves drift
// so gates-VALU of one wave overlaps MFMA of another.
// ---------------------------------------------------------------------------

typedef short v8s __attribute__((ext_vector_type(8)));   // 8 x bf16 bits (MFMA A/B frag)
typedef float v4f __attribute__((ext_vector_type(4)));   // MFMA C/D frag

#define DEV static __device__ __forceinline__
#define DT_THRESH 4096

DEV float b2f(unsigned short h) {
    union { unsigned int u; float f; } v; v.u = ((unsigned int)h) << 16; return v.f;
}
DEV unsigned short f2b(float f) {
    union { float f; unsigned int u; } v; v.f = f;
    unsigned int u = v.u;
    return (unsigned short)((u + 0x7fffu + ((u >> 16) & 1u)) >> 16);
}
DEV float sigf(float x) {
    x = fminf(fmaxf(x, -30.f), 30.f);
    return 1.f / (1.f + __expf(-x));
}
DEV float tanh_(float x) {
    x = fminf(fmaxf(x, -15.f), 15.f);
    float e = __expf(-2.f * x);
    return (1.f - e) / (1.f + e);
}

// ---------------------------------------------------------------------------
// K0a: dones decode (robust int32/bf16/byte) + zero the dtype-flag counter.
// ---------------------------------------------------------------------------
__global__ __launch_bounds__(1024) void dones_k(const void* __restrict__ raw,
                                                int* __restrict__ dst,
                                                int* __restrict__ dt) {
    __shared__ int bad_int, bad_bf;
    int tid = threadIdx.x;
    if (tid == 0) { bad_int = 0; bad_bf = 0; dt[0] = 0; }
    __syncthreads();
    const unsigned int* w = (const unsigned int*)raw;
    int li = 0, lb = 0;
    for (int i = tid; i < 32768; i += 1024) {
        unsigned int v = w[i];
        if (v > 1u) li = 1;
        unsigned int h0 = v & 0xffffu, h1 = v >> 16;
        if ((h0 != 0u && h0 != 0x3f80u) || (h1 != 0u && h1 != 0x3f80u)) lb = 1;
    }
    if (li) atomicOr(&bad_int, 1);
    if (lb) atomicOr(&bad_bf, 1);
    __syncthreads();
    int mode = (!bad_int) ? 0 : ((!bad_bf) ? 1 : 2);
    for (int e = tid; e < 131072; e += 1024) {
        int v;
        if (mode == 0)      v = (((const int*)raw)[e] != 0);
        else if (mode == 1) v = (((const unsigned short*)raw)[e] != 0);
        else                v = (((const unsigned char*)raw)[e] != 0);
        dst[e] = v;
    }
}

// ---------------------------------------------------------------------------
// K0b: float-dtype detect.
// ---------------------------------------------------------------------------
__global__ __launch_bounds__(256) void detect_k(const unsigned short* __restrict__ xr,
                                                int* __restrict__ dt) {
    int tid = blockIdx.x * 256 + threadIdx.x;   // 16384 threads
    int cnt = 0;
    for (int i = tid; i < (1 << 24); i += 16384) {
        unsigned int e = (xr[i] >> 7) & 0xffu;
        cnt += (e >= 140u);
    }
    for (int o = 32; o; o >>= 1) cnt += __shfl_down(cnt, o);
    if ((threadIdx.x & 63) == 0 && cnt) atomicAdd(dt, cnt);
}

// ---------------------------------------------------------------------------
// K0c: x -> bf16 canonical copy.
// ---------------------------------------------------------------------------
__global__ __launch_bounds__(256) void cvt_x_k(const void* __restrict__ xr,
                                               unsigned short* __restrict__ xb,
                                               const int* __restrict__ dt) {
    int fp32i = dt[0] > DT_THRESH;
    long i4 = (long)blockIdx.x * 256 + threadIdx.x;
    if (fp32i) {
        float4 v = ((const float4*)xr)[i4];
        uint2 p;
        p.x = (unsigned int)f2b(v.x) | ((unsigned int)f2b(v.y) << 16);
        p.y = (unsigned int)f2b(v.z) | ((unsigned int)f2b(v.w) << 16);
        ((uint2*)xb)[i4] = p;
    } else {
        ((uint2*)xb)[i4] = ((const uint2*)xr)[i4];
    }
}

// ---------------------------------------------------------------------------
// K0d: transpose (and dtype-convert) weight matrices W[R][C] -> WT[C][R] bf16.
// ---------------------------------------------------------------------------
struct TransArgs {
    const void* src[9];
    unsigned short* dst[9];
    int R[9];
    int C[9];
    int prefix[10];
    int total;
};

__global__ __launch_bounds__(256) void trans_kernel(TransArgs a, const int* __restrict__ dt) {
    int fp32i = dt[0] > DT_THRESH;
    int id = blockIdx.x * 256 + threadIdx.x;
    if (id >= a.total) return;
    int m = 0;
#pragma unroll
    for (int k = 0; k < 9; k++)
        if (id >= a.prefix[k + 1]) m = k + 1;
    int e = id - a.prefix[m];
    int C = a.C[m];
    int r = e / C, c = e % C;
    unsigned short v;
    if (fp32i) v = f2b(((const float*)a.src[m])[e]);
    else       v = ((const unsigned short*)a.src[m])[e];
    a.dst[m][c * a.R[m] + r] = v;
}

// ---------------------------------------------------------------------------
// Generic bf16 GEMM (verified since round 3).
// ---------------------------------------------------------------------------
template <int TN, int ACT, int OM>
__global__ __launch_bounds__(256) void gemm_k(const unsigned short* __restrict__ A,
                                              const unsigned short* __restrict__ BT,
                                              const unsigned short* __restrict__ bias,
                                              void* __restrict__ Cout, long coff,
                                              const int* __restrict__ dtf,
                                              int N, int K) {
    __shared__ unsigned short As[128][40];
    __shared__ unsigned short Bs[TN][40];
    const int tid = threadIdx.x;
    const int l = tid & 63, w = tid >> 6;
    const long m0 = (long)blockIdx.x * 128;
    const int n0 = blockIdx.y * TN;
    constexpr int NRT = (TN == 128) ? 4 : 2;
    constexpr int NCT = (TN == 128) ? 4 : 1;
    int fp32o = (OM == 1) ? (dtf[0] > DT_THRESH) : 0;

    v4f acc[NRT][NCT];
    for (int i = 0; i < NRT; i++)
        for (int j = 0; j < NCT; j++) acc[i][j] = v4f{0.f, 0.f, 0.f, 0.f};

    for (int kc = 0; kc < K; kc += 32) {
        {
            int row = tid >> 1, part = tid & 1;
            const uint4* src = (const uint4*)(A + (m0 + row) * K + kc + part * 16);
            uint4 v0 = src[0], v1 = src[1];
            *(uint4*)&As[row][part * 16] = v0;
            *(uint4*)&As[row][part * 16 + 8] = v1;
        }
        if (TN == 128) {
            int row = tid >> 1, part = tid & 1;
            const uint4* src = (const uint4*)(BT + (long)(n0 + row) * K + kc + part * 16);
            uint4 v0 = src[0], v1 = src[1];
            *(uint4*)&Bs[row][part * 16] = v0;
            *(uint4*)&Bs[row][part * 16 + 8] = v1;
        } else if (tid < 32) {
            int row = tid >> 1, part = tid & 1;
            const uint4* src = (const uint4*)(BT + (long)(n0 + row) * K + kc + part * 16);
            uint4 v0 = src[0], v1 = src[1];
            *(uint4*)&Bs[row][part * 16] = v0;
            *(uint4*)&Bs[row][part * 16 + 8] = v1;
        }
        __syncthreads();

        v8s af[NRT], bf[NCT];
#pragma unroll
        for (int i = 0; i < NRT; i++) {
            int rt = (TN == 128) ? ((w >> 1) * 4 + i) : (w * 2 + i);
            af[i] = *(const v8s*)&As[rt * 16 + (l & 15)][(l >> 4) * 8];
        }
#pragma unroll
        for (int j = 0; j < NCT; j++) {
            int ct = (TN == 128) ? ((w & 1) * 4 + j) : 0;
            bf[j] = *(const v8s*)&Bs[ct * 16 + (l & 15)][(l >> 4) * 8];
        }
#pragma unroll
        for (int i = 0; i < NRT; i++)
#pragma unroll
            for (int j = 0; j < NCT; j++)
                acc[i][j] = __builtin_amdgcn_mfma_f32_16x16x32_bf16(af[i], bf[j], acc[i][j], 0, 0, 0);
        __syncthreads();
    }

#pragma unroll
    for (int j = 0; j < NCT; j++) {
        int ct = (TN == 128) ? ((w & 1) * 4 + j) : 0;
        int col = ct * 16 + (l & 15);
        float bv = b2f(bias[n0 + col]);
#pragma unroll
        for (int i = 0; i < NRT; i++) {
            int rt = (TN == 128) ? ((w >> 1) * 4 + i) : (w * 2 + i);
#pragma unroll
            for (int q = 0; q < 4; q++) {
                long row = m0 + rt * 16 + (l >> 4) * 4 + q;
                float v = acc[i][j][q] + bv;
                if (ACT == 1) v = fmaxf(v, 0.f);
                if (ACT == 2) v = tanh_(v);
                long idx = coff + row * (long)N + n0 + col;
                if (OM == 1 && fp32o) ((float*)Cout)[idx] = v;
                else ((unsigned short*)Cout)[idx] = f2b(v);
            }
        }
    }
}

// ---------------------------------------------------------------------------
// K2: LSTM scan, exchange-free.  16 WGs x 1024 threads (16 waves, 4/SIMD).
// WG = one batch cluster (16 rows).  Wave w: hid slice w*16, all 4 gates.
// acc[g][q] = z_g(row=lq*4+q, hid=w*16+l15) -> gates are lane-local.
// B (WhT) streamed from L2 each step (2-deep reg dbuf); h in double-buffered
// XOR-swizzled LDS -> one __syncthreads per step.  No atomics, no polling.
// dones masking folded into the h write (h for step t+1 masked by dones[t+1])
// so the MFMA A-path needs no mask; c masked in-register with dones[t].
// ---------------------------------------------------------------------------
__global__ __launch_bounds__(1024, 4) void lstm_k(const unsigned short* __restrict__ xz,   // [512*256][1024]
                                                  const int* __restrict__ dones,           // [512][256] decoded
                                                  const void* __restrict__ h0c,
                                                  const void* __restrict__ h0h,
                                                  const unsigned short* __restrict__ WhT,  // [1024][256]
                                                  unsigned short* __restrict__ hs,         // [512*256][256] (bf16)
                                                  void* __restrict__ outv,
                                                  const int* __restrict__ dtf) {
    __shared__ unsigned short hlds[2][16][256];   // double-buffered h tile, XOR-swizzled

    const int tid = threadIdx.x;               // 0..1023
    const int l = tid & 63;
    const int w = tid >> 6;                    // wave 0..15 -> hid slice w*16
    const int cluster = blockIdx.x;            // 0..15
    const int bt = cluster * 16;
    const int fp32o = dtf[0] > DT_THRESH;
    const int l15 = l & 15;
    const int lq = l >> 4;
    const int hid = w * 16 + l15;

    // B-fragment base pointers (one per gate); frag (g,ks) at bp[g] + ks*32
    const unsigned short* bp[4];
#pragma unroll
    for (int g = 0; g < 4; g++)
        bp[g] = WhT + (long)(g * 256 + hid) * 256 + lq * 8;

    // ---- init: c/h0 load, dones[0] mask folded into the h tile
    float c[4], hcur[4] = {0.f, 0.f, 0.f, 0.f};
    int dn_cur[4], dn_nxt[4];
    unsigned short xzb[16];
#pragma unroll
    for (int q = 0; q < 4; q++) {
        int row = lq * 4 + q;
        long idx = (long)(bt + row) * 256 + hid;
        c[q] = fp32o ? ((const float*)h0c)[idx] : b2f(((const unsigned short*)h0c)[idx]);
        float h0 = fp32o ? ((const float*)h0h)[idx] : b2f(((const unsigned short*)h0h)[idx]);
        dn_cur[q] = dones[bt + row];           // dones[t=0]
        dn_nxt[q] = dones[256 + bt + row];     // dones[t=1]
        hlds[0][row][hid ^ ((row & 7) * 8)] = dn_cur[q] ? (unsigned short)0 : f2b(h0);
    }
    // xz prefetch for t=0
#pragma unroll
    for (int g = 0; g < 4; g++)
#pragma unroll
        for (int q = 0; q < 4; q++)
            xzb[g * 4 + q] = xz[(long)(bt + lq * 4 + q) * 1024 + g * 256 + hid];
    __syncthreads();

    for (int t = 0; t < 512; t++) {
        const int cur = t & 1, nxt = cur ^ 1;

        // ---- acc init from prefetched xz (bias already folded in by gemm_k)
        v4f acc[4];
#pragma unroll
        for (int g = 0; g < 4; g++)
#pragma unroll
            for (int q = 0; q < 4; q++) acc[g][q] = b2f(xzb[g * 4 + q]);

        // ---- issue xz prefetch for t+1 (consumed next step; ~1 step of slack)
        {
            int tn = (t < 511) ? t + 1 : t;
#pragma unroll
            for (int g = 0; g < 4; g++)
#pragma unroll
                for (int q = 0; q < 4; q++)
                    xzb[g * 4 + q] = xz[(long)(tn * 256 + bt + lq * 4 + q) * 1024 + g * 256 + hid];
        }

        // ---- MFMA over K=256: A from LDS h tile, B streamed from L2 (dbuf)
        v8s bb0[4], bb1[4];
#pragma unroll
        for (int g = 0; g < 4; g++) bb0[g] = *(const v8s*)(bp[g]);
#pragma unroll
        for (int ks = 0; ks < 8; ks++) {
            v8s a = *(const v8s*)&hlds[cur][l15][(ks * 32 + lq * 8) ^ ((l15 & 7) * 8)];
            if (ks + 1 < 8) {
#pragma unroll
                for (int g = 0; g < 4; g++) {
                    v8s nb = *(const v8s*)(bp[g] + (ks + 1) * 32);
                    if ((ks & 1) == 0) bb1[g] = nb; else bb0[g] = nb;
                }
            }
#pragma unroll
            for (int g = 0; g < 4; g++) {
                v8s bfr = ((ks & 1) == 0) ? bb0[g] : bb1[g];
                acc[g] = __builtin_amdgcn_mfma_f32_16x16x32_bf16(a, bfr, acc[g], 0, 0, 0);
            }
        }

        // ---- gates + state update (lane-local; no cross-wave exchange)
#pragma unroll
        for (int q = 0; q < 4; q++) {
            int row = lq * 4 + q;
            float zi = acc[0][q];
            float zf = acc[1][q];
            float zg = acc[2][q];
            float zo = acc[3][q];
            float cm = dn_cur[q] ? 0.f : c[q];
            float cn = sigf(zf) * cm + sigf(zi) * tanh_(zg);
            float h = sigf(zo) * tanh_(cn);
            c[q] = cn;
            hcur[q] = h;
            unsigned short hbits = f2b(h);
            // h for step t+1, masked by dones[t+1] (write into the OTHER buffer)
            hlds[nxt][row][hid ^ ((row & 7) * 8)] = dn_nxt[q] ? (unsigned short)0 : hbits;
            // packed hs history (unmasked h)
            unsigned int pr = (unsigned int)__shfl_xor((int)hbits, 1);
            if ((l & 1) == 0) {
                ((unsigned int*)hs)[((long)(t * 256 + bt + row)) * 128 + (hid >> 1)] =
                    (unsigned int)hbits | (pr << 16);
            }
        }
        // rotate dones prefetch
#pragma unroll
        for (int q = 0; q < 4; q++) dn_cur[q] = dn_nxt[q];
        {
            int tn2 = (t + 2 < 512) ? t + 2 : 511;
#pragma unroll
            for (int q = 0; q < 4; q++) dn_nxt[q] = dones[tn2 * 256 + bt + lq * 4 + q];
        }
        __syncthreads();   // writes to hlds[nxt] visible before step t+1 reads
    }

    // c_fin at out elems [0:65536], h_fin at [65536:131072]
#pragma unroll
    for (int q = 0; q < 4; q++) {
        int row = lq * 4 + q;
        long i1 = (long)(bt + row) * 256 + hid;
        long i2 = 65536 + i1;
        if (fp32o) {
            ((float*)outv)[i1] = c[q];
            ((float*)outv)[i2] = hcur[q];
        } else {
            ((unsigned short*)outv)[i1] = f2b(c[q]);
            ((unsigned short*)outv)[i2] = f2b(hcur[q]);
        }
    }
}

// ---------------------------------------------------------------------------
// value head: value[r] = v2[r] . Wc3 + bc3   (K=128, N=1)
// ---------------------------------------------------------------------------
__global__ __launch_bounds__(256) void value_k(const unsigned short* __restrict__ V2,
                                               const unsigned short* __restrict__ Wc3T,
                                               const unsigned short* __restrict__ bc3,
                                               void* __restrict__ outv,
                                               const int* __restrict__ dtf) {
    int tid = threadIdx.x;
    int l = tid & 63, w = tid >> 6;
    int fp32o = dtf[0] > DT_THRESH;
    long row = (long)blockIdx.x * 32 + w * 8 + (l >> 3);
    int sub = l & 7;
    const unsigned short* vp = V2 + row * 128 + sub * 16;
    float s = 0.f;
#pragma unroll
    for (int j = 0; j < 16; j++) s += b2f(vp[j]) * b2f(Wc3T[sub * 16 + j]);
    s += __shfl_xor(s, 1);
    s += __shfl_xor(s, 2);
    s += __shfl_xor(s, 4);
    if (sub == 0) {
        float v = s + b2f(bc3[0]);
        if (fp32o) ((float*)outv)[2228224 + row] = v;
        else ((unsigned short*)outv)[2228224 + row] = f2b(v);
    }
}

// ---------------------------------------------------------------------------
// host launcher
// ---------------------------------------------------------------------------
extern "C" void kernel_launch(void* const* d_in, const int* in_sizes, int n_in,
                              void* d_out, int out_size, void* d_ws, size_t ws_size,
                              hipStream_t stream) {
    const void* x             = d_in[0];
    const void* dones_raw     = d_in[1];
    const void* h0c           = d_in[2];
    const void* h0h           = d_in[3];
    const void* We  = d_in[4];
    const unsigned short* be  = (const unsigned short*)d_in[5];
    const void* Wi  = d_in[6];
    const void* Wh  = d_in[7];
    const unsigned short* bl  = (const unsigned short*)d_in[8];
    const void* Wa1 = d_in[9];
    const unsigned short* ba1 = (const unsigned short*)d_in[10];
    const void* Wa2 = d_in[11];
    const unsigned short* ba2 = (const unsigned short*)d_in[12];
    const void* Wa3 = d_in[13];
    const unsigned short* ba3 = (const unsigned short*)d_in[14];
    const void* Wc1 = d_in[15];
    const unsigned short* bc1 = (const unsigned short*)d_in[16];
    const void* Wc2 = d_in[17];
    const unsigned short* bc2 = (const unsigned short*)d_in[18];
    const void* Wc3 = d_in[19];
    const unsigned short* bc3 = (const unsigned short*)d_in[20];
    char* ws = (char*)d_ws;

    // workspace layout (bytes)
    unsigned short* WeT  = (unsigned short*)(ws + 0);          //   131072
    unsigned short* WiT  = (unsigned short*)(ws + 131072);     //   524288
    unsigned short* WhT  = (unsigned short*)(ws + 655360);     //   524288
    unsigned short* Wa1T = (unsigned short*)(ws + 1179648);    //    65536
    unsigned short* Wa2T = (unsigned short*)(ws + 1245184);    //    32768
    unsigned short* Wa3T = (unsigned short*)(ws + 1277952);    //     4096
    unsigned short* Wc1T = (unsigned short*)(ws + 1282048);    //    65536
    unsigned short* Wc2T = (unsigned short*)(ws + 1347584);    //    32768
    unsigned short* Wc3T = (unsigned short*)(ws + 1380352);    //      256
    int*            DT   = (int*)(ws + 1380608);               //       64
    unsigned int*   HB   = (unsigned int*)(ws + 1380672);      //   524288 (unused this round)
    int*            DN   = (int*)(ws + 1904960);               //   524288
    unsigned short* XB   = (unsigned short*)(ws + 2429248);    // 67108864
    unsigned short* E    = (unsigned short*)(ws + 69538112);   // 67108864
    unsigned short* XZ   = (unsigned short*)(ws + 136646976);  // 268435456
    unsigned short* HS   = (unsigned short*)(ws + 405082432);  // 67108864 -> ends 472191296
    unsigned short* H1   = XB;                                  // alias (XB dead post-E)
    unsigned short* H2   = XB + 16777216;
    (void)HB;

    TransArgs ta;
    {
        const void* srcs[9] = {We, Wi, Wh, Wa1, Wa2, Wa3, Wc1, Wc2, Wc3};
        unsigned short* dsts[9] = {WeT, WiT, WhT, Wa1T, Wa2T, Wa3T, Wc1T, Wc2T, Wc3T};
        int Rs[9] = {256, 256, 256, 256, 128, 128, 256, 128, 128};
        int Cs[9] = {256, 1024, 1024, 128, 128, 16, 128, 128, 1};
        int p = 0;
        for (int i = 0; i < 9; i++) {
            ta.src[i] = srcs[i];
            ta.dst[i] = dsts[i];
            ta.R[i] = Rs[i];
            ta.C[i] = Cs[i];
            ta.prefix[i] = p;
            p += Rs[i] * Cs[i];
        }
        ta.prefix[9] = p;
        ta.total = p;  // 690304
    }

    dones_k<<<1, 1024, 0, stream>>>(dones_raw, DN, DT);
    detect_k<<<64, 256, 0, stream>>>((const unsigned short*)x, DT);
    cvt_x_k<<<32768, 256, 0, stream>>>(x, XB, DT);
    trans_kernel<<<2697, 256, 0, stream>>>(ta, DT);

    // E = relu(x @ We + be)            [131072 x 256]
    gemm_k<128, 1, 0><<<dim3(1024, 2), 256, 0, stream>>>(XB, WeT, be, E, 0, nullptr, 256, 256);
    // XZ = E @ Wi + b_lstm             [131072 x 1024]
    gemm_k<128, 0, 0><<<dim3(1024, 8), 256, 0, stream>>>(E, WiT, bl, XZ, 0, nullptr, 1024, 256);
    // LSTM scan -> HS, c_fin, h_fin   (exchange-free: 16 WGs x 1024 threads)
    lstm_k<<<16, 1024, 0, stream>>>(XZ, DN, h0c, h0h, WhT, HS, d_out, DT);
    // actor head
    gemm_k<128, 2, 0><<<dim3(1024, 1), 256, 0, stream>>>(HS, Wa1T, ba1, H1, 0, nullptr, 128, 256);
    gemm_k<128, 2, 0><<<dim3(1024, 1), 256, 0, stream>>>(H1, Wa2T, ba2, H2, 0, nullptr, 128, 128);
    gemm_k<16, 0, 1><<<dim3(1024, 1), 256, 0, stream>>>(H2, Wa3T, ba3, d_out, 131072, DT, 16, 128);
    // critic head
    gemm_k<128, 2, 0><<<dim3(1024, 1), 256, 0, stream>>>(HS, Wc1T, bc1, H1, 0, nullptr, 128, 256);
    gemm_k<128, 2, 0><<<dim3(1024, 1), 256, 0, stream>>>(H1, Wc2T, bc2, H2, 0, nullptr, 128, 128);
    value_k<<<4096, 256, 0, stream>>>(H2, Wc3T, bc3, d_out, DT);
}